// Round 4
// baseline (92.218 us; speedup 1.0000x reference)
//
#include <hip/hip_runtime.h>
#include <hip/hip_fp16.h>

// Signature-kernel MMD, fused. R4: split-wave 4-rows-per-lane PDE.
// Lanes 0-31 = pair A, lanes 32-63 = pair B; each lane owns 4 consecutive
// rows of the 127-row K diagonal. One instruction advances BOTH pairs:
// per diagonal only 1 wave_shr1 (+1 cndmask to isolate the pair halves at
// lane 32) and 8 VALU; 3 fresh fp16 LDS reads per body (2 diagonals) for
// both pairs, all from one base pointer with uniform immediate offsets.
// Boundary K=1 / zero-outside emerge from the seed (verified R2/R3): all
// out-of-range inc reads are multiplied by exactly-zero state; garbage
// cells (j>126, row-127 slot) only ever feed garbage cells.

constexpr int S2  = 66;     // binc row stride (fp16 elems)
constexpr int PAD = 66;     // front pad (covers negative columns)
constexpr int BNA = 4352;   // per-pair buffer: PAD + 63*66 + rear margin, 8-mult

__global__ void zero_kernel(float* out) { out[0] = 0.0f; }

__device__ __forceinline__ float dpp_shr1(float v) {
    // result[l] = src[l-1], result[0] = 0
    return __builtin_bit_cast(float,
        __builtin_amdgcn_update_dpp(0, __builtin_bit_cast(int, v), 0x138, 0xF, 0xF, true));
}
__device__ __forceinline__ float dpp_shl1(float v) {
    // result[l] = src[l+1], result[63] = 0
    return __builtin_bit_cast(float,
        __builtin_amdgcn_update_dpp(0, __builtin_bit_cast(int, v), 0x130, 0xF, 0xF, true));
}
__device__ __forceinline__ float dot4(float4 a, float4 b) {
    return a.x * b.x + a.y * b.y + a.z * b.z + a.w * b.w;
}

// One body = diagonals d=2k-1, 2k. fA/fB/fC = (binc-1) for body k;
// Bp/Cp carry body k-1's B/C values. Updates rows 4m..4m+3 for both pairs.
#define BODY4(fA, fB, fC) {                               \
    float u1 = dpp_shr1(p13); u1 = mz ? 0.0f : u1;        \
    float c0 = (p10 + u1)  + up2 * fA;                    \
    float c1 = (p11 + p10) + p20 * Bp;                    \
    float c2 = (p12 + p11) + p21 * Bp;                    \
    float c3 = (p13 + p12) + p22 * Cp;                    \
    float u2 = dpp_shr1(c3); u2 = mz ? 0.0f : u2;         \
    float d0 = (c0 + u2) + u1  * fA;                      \
    float d1 = (c1 + c0) + p10 * fB;                      \
    float d2 = (c2 + c1) + p11 * Bp;                      \
    float d3 = (c3 + c2) + p12 * fC;                      \
    p20 = c0; p21 = c1; p22 = c2;                         \
    p10 = d0; p11 = d1; p12 = d2; p13 = d3;               \
    up2 = u2; Bp = fB; Cp = fC; }

__global__ __launch_bounds__(64) void sigpde_kernel(const float* __restrict__ x,
                                                    const float* __restrict__ y,
                                                    float* __restrict__ out) {
    __shared__ _Float16 binc[2][BNA];
    __shared__ float4 xs0[64], xs1[64];
    __shared__ float  xx0[64], xx1[64];

    const int lane = threadIdx.x;
    const int q0 = blockIdx.x;          // pair A
    const int q1 = blockIdx.x + 1536;   // pair B
    const int g0 = q0 >> 10, a0 = (q0 & 1023) >> 5, b0 = q0 & 31;
    const int g1 = q1 >> 10, a1 = (q1 & 1023) >> 5, b1 = q1 & 31;
    const float* A0 = (g0 == 2) ? y : x;  const float* B0 = (g0 == 0) ? x : y;
    const float* A1 = (g1 == 2) ? y : x;  const float* B1 = (g1 == 0) ? x : y;

    float4 xa0 = ((const float4*)(A0 + a0 * 256))[lane];
    float4 yv0 = ((const float4*)(B0 + b0 * 256))[lane];
    float4 xa1 = ((const float4*)(A1 + a1 * 256))[lane];
    float4 yv1 = ((const float4*)(B1 + b1 * 256))[lane];
    xs0[lane] = xa0; xx0[lane] = dot4(xa0, xa0);
    xs1[lane] = xa1; xx1[lane] = dot4(xa1, xa1);
    const float yy0 = dot4(yv0, yv0), yy1 = dot4(yv1, yv1);

    {   // zero both binc buffers (pads/gaps must be finite zeros)
        uint4* z = (uint4*)&binc[0][0];
        const uint4 zz = {0u, 0u, 0u, 0u};
        for (int i = lane; i < 2 * BNA / 8; i += 64) z[i] = zz;
    }
    __syncthreads();

    // Gram + double increments for both pairs (full wave, column = lane):
    // binc[p][u-1][lane] = 0.25*((G[u][l+1]-G[u][l]) - (G[u-1][l+1]-G[u-1][l]))
    float dp0 = 0.0f, dp1 = 0.0f;
    #pragma unroll 4
    for (int u = 0; u < 64; ++u) {
        float4 xu0 = xs0[u], xu1 = xs1[u];
        float t0 = xx0[u] + yy0 - 2.0f * dot4(xu0, yv0);
        float t1 = xx1[u] + yy1 - 2.0f * dot4(xu1, yv1);
        float gv0 = __expf(-0.5f * t0);
        float gv1 = __expf(-0.5f * t1);
        float d0 = dpp_shl1(gv0) - gv0;
        float d1 = dpp_shl1(gv1) - gv1;
        if (u > 0) {
            binc[0][PAD + (u - 1) * S2 + lane] = (_Float16)(0.25f * (d0 - dp0));
            binc[1][PAD + (u - 1) * S2 + lane] = (_Float16)(0.25f * (d1 - dp1));
        }
        dp0 = d0; dp1 = d1;
    }
    __syncthreads();

    // PDE: lane owns rows 4m..4m+3 (m = lane&31), pair selected by lane>>5.
    // Body-k fresh reads (both substeps served):
    //   A_k = binc[2m-1][k-2m-1] = pA[k]
    //   B_k = binc[2m  ][k-2m-1] = pA[k+66]
    //   C_k = binc[2m+1][k-2m-2] = pA[k+131]
    const int m = lane & 31;
    const bool mz = (m == 0);
    const _Float16* pA = &binc[lane >> 5][0] + (PAD + (2 * m - 1) * S2 - 2 * m - 1);

    // warmup: carries (body 0) + bodies 1,2 converted + bodies 3,4 raw
    float Bp  = (float)pA[66]  - 1.0f;
    float Cp  = (float)pA[131] - 1.0f;
    float fA0 = (float)pA[1]   - 1.0f, fB0 = (float)pA[67] - 1.0f, fC0 = (float)pA[132] - 1.0f;
    float fA1 = (float)pA[2]   - 1.0f, fB1 = (float)pA[68] - 1.0f, fC1 = (float)pA[133] - 1.0f;
    _Float16 hA2 = pA[3], hB2 = pA[69], hC2 = pA[134];
    _Float16 hA3 = pA[4], hB3 = pA[70], hC3 = pA[135];

    float p10 = mz ? 1.0f : 0.0f, p11 = 0.0f, p12 = 0.0f, p13 = 0.0f;
    float p20 = 0.0f, p21 = 0.0f, p22 = 0.0f, up2 = 0.0f;

    for (int k = 1; k <= 125; k += 2) {
        // convert bodies k+2, k+3 (loaded last iter)
        float gA2 = (float)hA2 - 1.0f, gB2 = (float)hB2 - 1.0f, gC2 = (float)hC2 - 1.0f;
        float gA3 = (float)hA3 - 1.0f, gB3 = (float)hB3 - 1.0f, gC3 = (float)hC3 - 1.0f;
        // prefetch bodies k+4, k+5
        hA2 = pA[k + 4]; hB2 = pA[k + 70]; hC2 = pA[k + 135];
        hA3 = pA[k + 5]; hB3 = pA[k + 71]; hC3 = pA[k + 136];
        // compute bodies k, k+1 (4 diagonals, both pairs)
        BODY4(fA0, fB0, fC0)
        BODY4(fA1, fB1, fC1)
        // rotate pipeline
        fA0 = gA2; fB0 = gB2; fC0 = gC2;
        fA1 = gA3; fB1 = gB3; fC1 = gC3;
    }

    // K[126,126] = row 126 = slot r2 of m==31, diagonal 252 (in p1).
    if (m == 31) {
        int g = (lane < 32) ? g0 : g1;
        float w = (g == 1) ? (-2.0f / 1024.0f) : (1.0f / 1024.0f);
        atomicAdd(out, w * p12);
    }
}

extern "C" void kernel_launch(void* const* d_in, const int* in_sizes, int n_in,
                              void* d_out, int out_size, void* d_ws, size_t ws_size,
                              hipStream_t stream) {
    const float* x = (const float*)d_in[0];
    const float* y = (const float*)d_in[1];
    float* out = (float*)d_out;
    (void)in_sizes; (void)n_in; (void)out_size; (void)d_ws; (void)ws_size;

    hipLaunchKernelGGL(zero_kernel, dim3(1), dim3(1), 0, stream, out);
    hipLaunchKernelGGL(sigpde_kernel, dim3(1536), dim3(64), 0, stream, x, y, out);
}

// Round 6
// 76.653 us; speedup vs baseline: 1.2031x; 1.2031x over previous
//
#include <hip/hip_runtime.h>

// Signature-kernel MMD, fused. R6: 4 waves/block x 1 pair/wave (3072 waves,
// 768 blocks -> 3 blocks/CU guaranteed co-residency, ~12 waves/CU), inner
// loop = R3-verified single-pair path: fp16 row-major binc (stride 66,
// zero-padded; out-of-window reads land on zeros and are multiplied by
// exactly-zero state - verified R2/R3/R4), DPP wave-shifts, depth-4-body
// software pipeline. Wave-private LDS slices -> no barriers in compute.
// Per-block LDS reduction -> 1 atomic per block (768 total).

constexpr int S2  = 66;     // binc row stride (fp16 elems)
constexpr int PAD = 64;     // front pad (covers negative column offsets)
constexpr int BNA = 4368;   // per-pair buffer (PAD + 63*66 + rear pad, 16B-mult)

__global__ void zero_kernel(float* out) { out[0] = 0.0f; }

__device__ __forceinline__ float dpp_shr1(float v) {
    // result[l] = src[l-1], result[0] = 0
    return __builtin_bit_cast(float,
        __builtin_amdgcn_update_dpp(0, __builtin_bit_cast(int, v), 0x138, 0xF, 0xF, true));
}
__device__ __forceinline__ float dpp_shl1(float v) {
    // result[l] = src[l+1], result[63] = 0
    return __builtin_bit_cast(float,
        __builtin_amdgcn_update_dpp(0, __builtin_bit_cast(int, v), 0x130, 0xF, 0xF, true));
}
__device__ __forceinline__ float dot4(float4 a, float4 b) {
    return a.x * b.x + a.y * b.y + a.z * b.z + a.w * b.w;
}

// Two PDE substeps (antidiagonals 2k-1, 2k); ef/of are RAW binc values.
// State: p1E,p1O (diag d-1), p2E (E diag d-2), up2 (shr1 of O diag d-2),
// oP (previous body's of). Verified in R3.
#define BODY(ef, of) {                                 \
    float up1 = dpp_shr1(p1O);                         \
    float cE  = (up1 - up2) + p1E + up2 * (ef);        \
    float cO  = (p1E - p2E) + p1O + p2E * oP;          \
    float nu2 = up1, np2 = p1E;                        \
    p1E = cE; p1O = cO;                                \
    up1 = dpp_shr1(p1O);                               \
    cE  = (up1 - nu2) + p1E + nu2 * (ef);              \
    cO  = (p1E - np2) + p1O + np2 * (of);              \
    up2 = up1; p2E = p1E; p1E = cE; p1O = cO;          \
    oP  = (of); }

__global__ __launch_bounds__(256) void sigpde_kernel(const float* __restrict__ x,
                                                     const float* __restrict__ y,
                                                     float* __restrict__ out) {
    __shared__ __align__(16) _Float16 binc[4][BNA];   // 34944 B
    __shared__ float4 xs[4][64];                      //  4096 B
    __shared__ float  xxs[4][64];                     //  1024 B
    __shared__ float  partial[4];

    const int lane = threadIdx.x & 63;
    const int wid  = threadIdx.x >> 6;
    const int p = blockIdx.x * 4 + wid;     // 0..3071
    const int g = p >> 10;                  // 0: xx, 1: xy, 2: yy
    const int q = p & 1023;
    const int a = q >> 5, b = q & 31;
    const float* Ab = (g == 2) ? y : x;
    const float* Bb = (g == 0) ? x : y;

    _Float16* bw = &binc[wid][0];

    float4 xa = ((const float4*)(Ab + a * 256))[lane];
    float4 yv = ((const float4*)(Bb + b * 256))[lane];
    xs[wid][lane]  = xa;
    xxs[wid][lane] = dot4(xa, xa);
    const float yy = dot4(yv, yv);

    {   // zero this wave's buffer (pads/gaps must be finite zeros)
        uint4* z = (uint4*)bw;
        const uint4 zz = {0u, 0u, 0u, 0u};
        for (int i = lane; i < BNA / 8; i += 64) z[i] = zz;
    }
    // No barrier: all LDS below is wave-private; same-wave ds ordering
    // is guaranteed via lgkmcnt.

    // Gram + double increments (column = lane):
    // binc[u-1][lane] = 0.25*((G[u][l+1]-G[u][l]) - (G[u-1][l+1]-G[u-1][l]))
    float dp = 0.0f;
    #pragma unroll 4
    for (int u = 0; u < 64; ++u) {
        float4 xu = xs[wid][u];            // broadcast read
        float t = xxs[wid][u] + yy - 2.0f * dot4(xu, yv);
        float gv = __expf(-0.5f * t);
        float d = dpp_shl1(gv) - gv;
        if (u > 0) bw[PAD + (u - 1) * S2 + lane] = (_Float16)(0.25f * (d - dp));
        dp = d;
    }

    // Goursat PDE: lane owns rows iE=2l, iO=2l+1; body k = diagonals 2k-1,2k.
    // Body k reads eA[k-1] = binc[l-1][k-1-l], oA[k-1] = binc[l][k-1-l]
    // (column offset folded into base pointer). Out-of-window -> zeros.
    const int rE = (lane >= 1) ? lane - 1 : 0;
    const int rO = (lane <= 62) ? lane : 62;
    const _Float16* eA = bw + PAD + rE * S2 - lane;
    const _Float16* oA = bw + PAD + rO * S2 - lane;

    float p1E = (lane == 0) ? 1.0f : 0.0f;  // diag 0 seed: K[0,0]=1
    float p1O = 0.0f, p2E = 0.0f, up2 = 0.0f, oP = 0.0f;

    // warmup: bodies 1,2 converted; bodies 3,4 in flight
    _Float16 he2 = eA[2], ho2 = oA[2], he3 = eA[3], ho3 = oA[3];
    float fe0 = (float)eA[0], fo0 = (float)oA[0];
    float fe1 = (float)eA[1], fo1 = (float)oA[1];

    #pragma unroll 2
    for (int k = 1; k <= 125; k += 2) {
        // convert bodies k+2, k+3 (loaded last iteration)
        float ge2 = (float)he2, go2 = (float)ho2;
        float ge3 = (float)he3, go3 = (float)ho3;
        // prefetch bodies k+4, k+5
        he2 = eA[k + 3]; ho2 = oA[k + 3];
        he3 = eA[k + 4]; ho3 = oA[k + 4];
        // compute bodies k, k+1
        BODY(fe0, fo0)
        BODY(fe1, fo1)
        // rotate pipeline
        fe0 = ge2; fo0 = go2; fe1 = ge3; fo1 = go3;
    }

    // K[126,126] = lane 63's E slot after diagonal 252.
    if (lane == 63) {
        float w = (g == 1) ? (-2.0f / 1024.0f) : (1.0f / 1024.0f);
        partial[wid] = w * p1E;
    }
    __syncthreads();
    if (threadIdx.x == 0) {
        atomicAdd(out, (partial[0] + partial[1]) + (partial[2] + partial[3]));
    }
}

extern "C" void kernel_launch(void* const* d_in, const int* in_sizes, int n_in,
                              void* d_out, int out_size, void* d_ws, size_t ws_size,
                              hipStream_t stream) {
    const float* x = (const float*)d_in[0];
    const float* y = (const float*)d_in[1];
    float* out = (float*)d_out;
    (void)in_sizes; (void)n_in; (void)out_size; (void)d_ws; (void)ws_size;

    hipLaunchKernelGGL(zero_kernel, dim3(1), dim3(1), 0, stream, out);
    hipLaunchKernelGGL(sigpde_kernel, dim3(768), dim3(256), 0, stream, x, y, out);
}